// Round 12
// baseline (29.029 us; speedup 1.0000x reference)
//
#include <hip/hip_runtime.h>

#define K_SAMP 256
#define D_HID 64
#define SCALER_FE 7.0f

typedef _Float16 half8  __attribute__((ext_vector_type(8)));
typedef __fp16   fp16x2 __attribute__((ext_vector_type(2)));
typedef float    f32x4  __attribute__((ext_vector_type(4)));

union H8U { half8 h; uint u[4]; };
union H8P { fp16x2 h2[4]; half8 h8; };

__device__ __forceinline__ half8 h8zero() {
    half8 a;
    #pragma unroll
    for (int j = 0; j < 8; ++j) a[j] = (_Float16)0.f;
    return a;
}

// DPP add: x += (x shifted by dpp_ctrl); shifted-out lanes contribute 0.
#define DPP_ADD(x, ctrl, rowmask)                                              \
    (x) += __int_as_float(__builtin_amdgcn_update_dpp(                         \
        0, __float_as_int(x), (ctrl), (rowmask), 0xf, false))

// Inclusive 64-lane scan (VALU-only).
__device__ __forceinline__ float dpp_scan_incl(float x) {
    DPP_ADD(x, 0x111, 0xf);   // row_shr:1
    DPP_ADD(x, 0x112, 0xf);   // row_shr:2
    DPP_ADD(x, 0x114, 0xf);   // row_shr:4
    DPP_ADD(x, 0x118, 0xf);   // row_shr:8
    DPP_ADD(x, 0x142, 0xa);   // row_bcast15 -> rows 1,3
    DPP_ADD(x, 0x143, 0xc);   // row_bcast31 -> rows 2,3
    return x;                 // lane 63 holds the 64-lane total
}

// ============================ KERNEL 1: MLP ================================
// Block = 1 ray = 4 waves; wave wv computes samples [64*wv, 64*wv+64) as
// 4 MFMA tiles of 16. No scan, no exp, no cross-wave coupling (one barrier
// for fragment staging only). Writes {fe, tex0..2} (float4) to ws[n].
__global__ __launch_bounds__(256, 6)
void volrend_mlp(const float* __restrict__ ray_start,
                 const float* __restrict__ ray_dir,
                 const float* __restrict__ depth,
                 const float* __restrict__ dists,
                 const int*   __restrict__ vidx,
                 const float* __restrict__ vcol_tab,
                 const float* __restrict__ W1,
                 const float* __restrict__ b1,
                 const float* __restrict__ w_sigma,
                 const float* __restrict__ b_sigma,
                 const float* __restrict__ W_tex,
                 const float* __restrict__ b_tex,
                 float4* __restrict__ ws) {
    __shared__ uint sFragP[4][6 * 64];       // component planes, conflict-free

    const int tid  = threadIdx.x;
    const int lane = tid & 63;
    const int wv   = tid >> 6;
    const int ray  = blockIdx.x;
    const int m    = lane & 15;
    const int g    = lane >> 4;

    // --- wave 0: build ray-independent fragments into LDS ---
    if (tid < 64) {
        #pragma unroll
        for (int tt = 0; tt < 4; ++tt) {
            const int dim = 8 * (m >> 2) + (m & 3) + 4 * (tt & 1) + 32 * (tt >> 1);
            half8 a = h8zero();
            if (g == 0) {
                #pragma unroll
                for (int j = 0; j < 6; ++j) a[j] = (_Float16)W1[j * D_HID + dim];
                a[6] = (_Float16)b1[dim];
            }
            H8U c; c.h = a;
            #pragma unroll
            for (int k = 0; k < 4; ++k) sFragP[k][tt * 64 + lane] = c.u[k];
        }
        half8 a2a = h8zero(), a2b = h8zero();
        if (m < 4) {
            const int c = (m >= 1) ? (m - 1) : 0;
            #pragma unroll
            for (int j = 0; j < 8; ++j) {
                const int d = 8 * g + j;
                a2a[j] = (_Float16)((m == 0) ? w_sigma[d]      : W_tex[d * 3 + c]);
                a2b[j] = (_Float16)((m == 0) ? w_sigma[d + 32] : W_tex[(d + 32) * 3 + c]);
            }
        }
        H8U ca; ca.h = a2a;
        H8U cb; cb.h = a2b;
        #pragma unroll
        for (int k = 0; k < 4; ++k) {
            sFragP[k][4 * 64 + lane] = ca.u[k];
            sFragP[k][5 * 64 + lane] = cb.u[k];
        }
    }

    // --- per-ray uniforms (block-uniform -> scalar loads) ---
    const float rs0 = ray_start[ray * 3 + 0];
    const float rs1 = ray_start[ray * 3 + 1];
    const float rs2 = ray_start[ray * 3 + 2];
    const float rd0 = ray_dir[ray * 3 + 0];
    const float rd1 = ray_dir[ray * 3 + 1];
    const float rd2 = ray_dir[ray * 3 + 2];
    const float bs  = b_sigma[0];
    const float bt0 = b_tex[0], bt1 = b_tex[1], bt2 = b_tex[2];

    __syncthreads();

    half8 a1[4];
    #pragma unroll
    for (int tt = 0; tt < 4; ++tt) {
        H8U c;
        #pragma unroll
        for (int k = 0; k < 4; ++k) c.u[k] = sFragP[k][tt * 64 + lane];
        a1[tt] = c.h;
    }
    H8U ca, cb;
    #pragma unroll
    for (int k = 0; k < 4; ++k) {
        ca.u[k] = sFragP[k][4 * 64 + lane];
        cb.u[k] = sFragP[k][5 * 64 + lane];
    }
    const half8 a2a = ca.h;
    const half8 a2b = cb.h;

    f32x4 oinit = {0.f, 0.f, 0.f, 0.f};
    if (g == 0) { oinit[0] = bs; oinit[1] = bt0; oinit[2] = bt1; oinit[3] = bt2; }
    const f32x4 zero4 = {0.f, 0.f, 0.f, 0.f};

    const fp16x2 hc12 = __builtin_amdgcn_cvt_pkrtz(rd1, rd2);
    const fp16x2 hc3  = __builtin_amdgcn_cvt_pkrtz(1.0f, 0.0f);

    const size_t rayBase = (size_t)ray * K_SAMP;

    #pragma unroll
    for (int t = 0; t < 4; ++t) {
        const int   n   = (wv << 6) + 16 * t + m;
        const float dpt = depth[rayBase + n];
        const float fx = fmaf(rd0, dpt, rs0);
        const float fy = fmaf(rd1, dpt, rs1);
        const float fz = fmaf(rd2, dpt, rs2);
        H8P bb;
        bb.h2[0] = __builtin_amdgcn_cvt_pkrtz(fx, fy);
        bb.h2[1] = __builtin_amdgcn_cvt_pkrtz(fz, rd0);
        bb.h2[2] = hc12;
        bb.h2[3] = hc3;
        const f32x4 h0 = __builtin_amdgcn_mfma_f32_16x16x32_f16(a1[0], bb.h8, zero4, 0, 0, 0);
        const f32x4 h1 = __builtin_amdgcn_mfma_f32_16x16x32_f16(a1[1], bb.h8, zero4, 0, 0, 0);
        const f32x4 h2 = __builtin_amdgcn_mfma_f32_16x16x32_f16(a1[2], bb.h8, zero4, 0, 0, 0);
        const f32x4 h3 = __builtin_amdgcn_mfma_f32_16x16x32_f16(a1[3], bb.h8, zero4, 0, 0, 0);

        H8P p2a, p2b;
        p2a.h2[0] = __builtin_amdgcn_cvt_pkrtz(fmaxf(h0[0], 0.f), fmaxf(h0[1], 0.f));
        p2a.h2[1] = __builtin_amdgcn_cvt_pkrtz(fmaxf(h0[2], 0.f), fmaxf(h0[3], 0.f));
        p2a.h2[2] = __builtin_amdgcn_cvt_pkrtz(fmaxf(h1[0], 0.f), fmaxf(h1[1], 0.f));
        p2a.h2[3] = __builtin_amdgcn_cvt_pkrtz(fmaxf(h1[2], 0.f), fmaxf(h1[3], 0.f));
        p2b.h2[0] = __builtin_amdgcn_cvt_pkrtz(fmaxf(h2[0], 0.f), fmaxf(h2[1], 0.f));
        p2b.h2[1] = __builtin_amdgcn_cvt_pkrtz(fmaxf(h2[2], 0.f), fmaxf(h2[3], 0.f));
        p2b.h2[2] = __builtin_amdgcn_cvt_pkrtz(fmaxf(h3[0], 0.f), fmaxf(h3[1], 0.f));
        p2b.h2[3] = __builtin_amdgcn_cvt_pkrtz(fmaxf(h3[2], 0.f), fmaxf(h3[3], 0.f));

        f32x4 o = oinit;
        o = __builtin_amdgcn_mfma_f32_16x16x32_f16(a2a, p2a.h8, o, 0, 0, 0);
        o = __builtin_amdgcn_mfma_f32_16x16x32_f16(a2b, p2b.h8, o, 0, 0, 0);

        if (g == 0) {
            const float dstv = dists[rayBase + n];
            const int   viv  = vidx[rayBase + n];
            const bool  mk   = (viv != -1);
            const int   vb   = (mk ? viv : 0) * 3;
            float fe = 0.f, tA = 0.f, tB = 0.f, tC = 0.f;
            if (mk) {
                fe = fmaxf(o[0], 0.f) * dstv * SCALER_FE;
                tA = o[1] + vcol_tab[vb + 0];
                tB = o[2] + vcol_tab[vb + 1];
                tC = o[3] + vcol_tab[vb + 2];
            }
            ws[rayBase + n] = make_float4(fe, tA, tB, tC);
        }
    }
}

// ========================= KERNEL 2: COMPOSITE =============================
// One ray per wave, 4 rays per block, no LDS. Lane L owns samples L+64s
// (interleaved chunks). 4 DPP chunk-scans + chunk-total combine -> probs;
// 5 DPP reductions -> ray outputs (lane 63 writes).
__global__ __launch_bounds__(256, 8)
void volrend_comp(const float4* __restrict__ ws,
                  const float*  __restrict__ depth,
                  float* __restrict__ out_colors,
                  float* __restrict__ out_depths,
                  float* __restrict__ out_missed,
                  float* __restrict__ out_probs) {
    const int lane = threadIdx.x & 63;
    const int wv   = threadIdx.x >> 6;
    const int ray  = __builtin_amdgcn_readfirstlane(blockIdx.x * 4 + wv);
    const size_t rayBase = (size_t)ray * K_SAMP;

    float fe_[4], tA[4], tB[4], tC[4], dep_[4];
    #pragma unroll
    for (int s = 0; s < 4; ++s) {
        const int n = lane + 64 * s;
        const float4 f4 = ws[rayBase + n];
        dep_[s] = depth[rayBase + n];
        fe_[s] = f4.x; tA[s] = f4.y; tB[s] = f4.z; tC[s] = f4.w;
    }

    float incl[4], tot[4];
    #pragma unroll
    for (int s = 0; s < 4; ++s) incl[s] = dpp_scan_incl(fe_[s]);
    #pragma unroll
    for (int s = 0; s < 4; ++s) tot[s] = __shfl(incl[s], 63, 64);

    float p_[4];
    float base = 0.f;
    #pragma unroll
    for (int s = 0; s < 4; ++s) {
        const float e = base + incl[s] - fe_[s];
        p_[s] = (1.0f - __expf(-fe_[s])) * __expf(-e);
        base += tot[s];
    }
    #pragma unroll
    for (int s = 0; s < 4; ++s) {
        out_probs[rayBase + lane + 64 * s] = p_[s];
    }

    float sp = dpp_scan_incl(p_[0] + p_[1] + p_[2] + p_[3]);
    float sd = dpp_scan_incl(dep_[0] * p_[0] + dep_[1] * p_[1] +
                             dep_[2] * p_[2] + dep_[3] * p_[3]);
    float c0 = dpp_scan_incl(tA[0] * p_[0] + tA[1] * p_[1] + tA[2] * p_[2] + tA[3] * p_[3]);
    float c1 = dpp_scan_incl(tB[0] * p_[0] + tB[1] * p_[1] + tB[2] * p_[2] + tB[3] * p_[3]);
    float c2 = dpp_scan_incl(tC[0] * p_[0] + tC[1] * p_[1] + tC[2] * p_[2] + tC[3] * p_[3]);
    if (lane == 63) {
        out_colors[ray * 3 + 0] = c0;
        out_colors[ray * 3 + 1] = c1;
        out_colors[ray * 3 + 2] = c2;
        out_depths[ray] = sd;
        out_missed[ray] = 1.0f - sp;
    }
}

extern "C" void kernel_launch(void* const* d_in, const int* in_sizes, int n_in,
                              void* d_out, int out_size, void* d_ws, size_t ws_size,
                              hipStream_t stream) {
    const float* ray_start  = (const float*)d_in[0];
    const float* ray_dir    = (const float*)d_in[1];
    const float* depth      = (const float*)d_in[2];
    const float* dists      = (const float*)d_in[3];
    const int*   vidx       = (const int*)d_in[4];
    const float* vcol       = (const float*)d_in[5];
    const float* W1         = (const float*)d_in[6];
    const float* b1         = (const float*)d_in[7];
    const float* w_sigma    = (const float*)d_in[8];
    const float* b_sigma    = (const float*)d_in[9];
    const float* W_tex      = (const float*)d_in[10];
    const float* b_tex      = (const float*)d_in[11];

    const int N = in_sizes[0] / 3;       // 4096 rays
    float* out        = (float*)d_out;
    float* out_colors = out;
    float* out_depths = out + (size_t)N * 3;
    float* out_missed = out + (size_t)N * 3 + N;
    float* out_probs  = out + (size_t)N * 3 + 2 * (size_t)N;
    float4* ws = (float4*)d_ws;          // N*K_SAMP*16 B = 16.8 MB <= ws_size

    volrend_mlp<<<N, 256, 0, stream>>>(
        ray_start, ray_dir, depth, dists, vidx, vcol,
        W1, b1, w_sigma, b_sigma, W_tex, b_tex, ws);
    volrend_comp<<<N / 4, 256, 0, stream>>>(
        ws, depth, out_colors, out_depths, out_missed, out_probs);
}

// Round 13
// 18.970 us; speedup vs baseline: 1.5303x; 1.5303x over previous
//
#include <hip/hip_runtime.h>

#define K_SAMP 256
#define D_HID 64
#define SCALER_FE 7.0f

typedef _Float16 half8  __attribute__((ext_vector_type(8)));
typedef __fp16   fp16x2 __attribute__((ext_vector_type(2)));
typedef float    f32x16 __attribute__((ext_vector_type(16)));

union H8U { half8 h; uint u[4]; };
union H8P { fp16x2 h2[4]; half8 h8; };

__device__ __forceinline__ half8 h8zero() {
    half8 a;
    #pragma unroll
    for (int j = 0; j < 8; ++j) a[j] = (_Float16)0.f;
    return a;
}

// DPP add: x += (x shifted by dpp_ctrl); shifted-out lanes contribute 0.
#define DPP_ADD(x, ctrl, rowmask)                                              \
    (x) += __int_as_float(__builtin_amdgcn_update_dpp(                         \
        0, __float_as_int(x), (ctrl), (rowmask), 0xf, false))

// Inclusive 64-lane scan (VALU-only).
__device__ __forceinline__ float dpp_scan_incl(float x) {
    DPP_ADD(x, 0x111, 0xf);   // row_shr:1
    DPP_ADD(x, 0x112, 0xf);   // row_shr:2
    DPP_ADD(x, 0x114, 0xf);   // row_shr:4
    DPP_ADD(x, 0x118, 0xf);   // row_shr:8
    DPP_ADD(x, 0x142, 0xa);   // row_bcast15 -> rows 1,3
    DPP_ADD(x, 0x143, 0xc);   // row_bcast31 -> rows 2,3
    return x;                 // lane 63 holds the 64-lane total
}

// R9 structure (1 ray/wave, 4 rays/block, LDS frag staging, SoA sOut,
// interleaved DPP epilogue) with the MLP moved to 32x32x16 f16 MFMA:
// per tile of 32 samples: layer1 = 2 MFMA (dims 0-63 via permuted A1 tiles),
// layer2 = 4 MFMA (K=16 each). Dim permutation
//   dim(T,x) = 16*(x>>3) + 8*((x>>2)&1) + 4*T + (x&3)
// makes layer1's C regs land exactly in layer2's B slots (k=(l>>5)*8+j,
// q=r>>2, j=4T+(r&3)); samples stay lane-resident (col = lane&31).
__global__ __launch_bounds__(256, 4)
void volrend_kernel(const float* __restrict__ ray_start,
                    const float* __restrict__ ray_dir,
                    const float* __restrict__ depth,
                    const float* __restrict__ dists,
                    const int*   __restrict__ vidx,
                    const float* __restrict__ vcol_tab,
                    const float* __restrict__ W1,
                    const float* __restrict__ b1,
                    const float* __restrict__ w_sigma,
                    const float* __restrict__ b_sigma,
                    const float* __restrict__ W_tex,
                    const float* __restrict__ b_tex,
                    float* __restrict__ out_colors,
                    float* __restrict__ out_depths,
                    float* __restrict__ out_missed,
                    float* __restrict__ out_probs) {
    __shared__ uint  sFragP[4][6 * 64];      // planes: a1[0],a1[1],a2[0..3]
    __shared__ float sOutP[4][4 * K_SAMP];   // SoA {sig,t0,t1,t2}

    const int tid  = threadIdx.x;
    const int lane = tid & 63;
    const int wv   = tid >> 6;
    const int ray  = __builtin_amdgcn_readfirstlane(blockIdx.x * 4 + wv);
    const int col  = lane & 31;              // sample col inside 32-tile
    const int g2   = lane >> 5;              // K-slice group (0/1)

    // --- wave 0: build fragments into LDS (ray-independent, lane-indexed) ---
    if (tid < 64) {
        const int x = lane & 31;
        // A1 tiles T=0,1: row x, k=j (lanes<32 only; k=8..15 are zero)
        #pragma unroll
        for (int T = 0; T < 2; ++T) {
            half8 a = h8zero();
            if (lane < 32) {
                const int dim = 16 * (x >> 3) + 8 * ((x >> 2) & 1) + 4 * T + (x & 3);
                #pragma unroll
                for (int j = 0; j < 6; ++j) a[j] = (_Float16)W1[j * D_HID + dim];
                a[6] = (_Float16)b1[dim];
            }
            H8U c; c.h = a;
            #pragma unroll
            for (int k = 0; k < 4; ++k) sFragP[k][T * 64 + lane] = c.u[k];
        }
        // A2[q]: rows 0..3 = {sigma, tex0..2}; value j -> dim = 16q + 8*g2 + j
        #pragma unroll
        for (int q = 0; q < 4; ++q) {
            half8 a = h8zero();
            if (x < 4) {
                const int dbase = 16 * q + 8 * (lane >> 5);
                #pragma unroll
                for (int j = 0; j < 8; ++j) {
                    const int d = dbase + j;
                    a[j] = (_Float16)((x == 0) ? w_sigma[d] : W_tex[d * 3 + (x - 1)]);
                }
            }
            H8U c; c.h = a;
            #pragma unroll
            for (int k = 0; k < 4; ++k) sFragP[k][(2 + q) * 64 + lane] = c.u[k];
        }
    }

    // --- per-ray uniforms (wave-uniform -> scalar loads) ---
    const float rs0 = ray_start[ray * 3 + 0];
    const float rs1 = ray_start[ray * 3 + 1];
    const float rs2 = ray_start[ray * 3 + 2];
    const float rd0 = ray_dir[ray * 3 + 0];
    const float rd1 = ray_dir[ray * 3 + 1];
    const float rd2 = ray_dir[ray * 3 + 2];
    const float bs  = b_sigma[0];
    const float bt0 = b_tex[0], bt1 = b_tex[1], bt2 = b_tex[2];

    // --- prefetch epilogue inputs, interleaved ownership (lane + 64s) ---
    const size_t rayBase = (size_t)ray * K_SAMP;
    float dep_[4], dst_[4];
    int   vi_[4];
    #pragma unroll
    for (int s = 0; s < 4; ++s) {
        const int n = lane + 64 * s;
        dep_[s] = depth[rayBase + n];
        dst_[s] = dists[rayBase + n];
        vi_[s]  = vidx[rayBase + n];
    }
    bool  msk[4];
    float vc[4][3];
    #pragma unroll
    for (int s = 0; s < 4; ++s) {
        msk[s] = (vi_[s] != -1);
        const int b = (msk[s] ? vi_[s] : 0) * 3;
        vc[s][0] = vcol_tab[b + 0];
        vc[s][1] = vcol_tab[b + 1];
        vc[s][2] = vcol_tab[b + 2];
    }

    __syncthreads();                         // frag staging visible

    half8 a1[2], a2[4];
    #pragma unroll
    for (int T = 0; T < 2; ++T) {
        H8U c;
        #pragma unroll
        for (int k = 0; k < 4; ++k) c.u[k] = sFragP[k][T * 64 + lane];
        a1[T] = c.h;
    }
    #pragma unroll
    for (int q = 0; q < 4; ++q) {
        H8U c;
        #pragma unroll
        for (int k = 0; k < 4; ++k) c.u[k] = sFragP[k][(2 + q) * 64 + lane];
        a2[q] = c.h;
    }

    f32x16 zero16;
    #pragma unroll
    for (int k = 0; k < 16; ++k) zero16[k] = 0.f;
    f32x16 oinit = zero16;
    if (lane < 32) { oinit[0] = bs; oinit[1] = bt0; oinit[2] = bt1; oinit[3] = bt2; }

    const fp16x2 hc12 = __builtin_amdgcn_cvt_pkrtz(rd1, rd2);
    const fp16x2 hc3  = __builtin_amdgcn_cvt_pkrtz(1.0f, 0.0f);
    const half8  bnull = h8zero();

    // --- 8 sample-tiles of 32 ---
    #pragma unroll 2
    for (int t = 0; t < 8; ++t) {
        const int   n   = 32 * t + col;
        const float dpt = depth[rayBase + n];
        const float fx = fmaf(rd0, dpt, rs0);
        const float fy = fmaf(rd1, dpt, rs1);
        const float fz = fmaf(rd2, dpt, rs2);
        H8P bbu;
        bbu.h2[0] = __builtin_amdgcn_cvt_pkrtz(fx, fy);
        bbu.h2[1] = __builtin_amdgcn_cvt_pkrtz(fz, rd0);
        bbu.h2[2] = hc12;
        bbu.h2[3] = hc3;
        const half8 bb = (lane < 32) ? bbu.h8 : bnull;   // k=8..15 are zero

        const f32x16 c1a = __builtin_amdgcn_mfma_f32_32x32x16_f16(a1[0], bb, zero16, 0, 0, 0);
        const f32x16 c1b = __builtin_amdgcn_mfma_f32_32x32x16_f16(a1[1], bb, zero16, 0, 0, 0);

        f32x16 o = oinit;
        #pragma unroll
        for (int q = 0; q < 4; ++q) {
            H8P b2;
            b2.h2[0] = __builtin_amdgcn_cvt_pkrtz(fmaxf(c1a[4 * q + 0], 0.f),
                                                  fmaxf(c1a[4 * q + 1], 0.f));
            b2.h2[1] = __builtin_amdgcn_cvt_pkrtz(fmaxf(c1a[4 * q + 2], 0.f),
                                                  fmaxf(c1a[4 * q + 3], 0.f));
            b2.h2[2] = __builtin_amdgcn_cvt_pkrtz(fmaxf(c1b[4 * q + 0], 0.f),
                                                  fmaxf(c1b[4 * q + 1], 0.f));
            b2.h2[3] = __builtin_amdgcn_cvt_pkrtz(fmaxf(c1b[4 * q + 2], 0.f),
                                                  fmaxf(c1b[4 * q + 3], 0.f));
            o = __builtin_amdgcn_mfma_f32_32x32x16_f16(a2[q], b2.h8, o, 0, 0, 0);
        }

        if (lane < 32) {
            const int idx = (wv << 8) + n;
            sOutP[0][idx] = o[0];
            sOutP[1][idx] = o[1];
            sOutP[2][idx] = o[2];
            sOutP[3][idx] = o[3];
        }
    }

    // --- epilogue: same-wave LDS read-back, lane-stride-1 (R9-verified) ---
    float fe_[4], tA[4], tB[4], tC[4];
    #pragma unroll
    for (int s = 0; s < 4; ++s) {
        const int idx = (wv << 8) + lane + 64 * s;
        const float sg = sOutP[0][idx];
        const float u0 = sOutP[1][idx];
        const float u1 = sOutP[2][idx];
        const float u2 = sOutP[3][idx];
        if (msk[s]) {
            fe_[s] = fmaxf(sg, 0.f) * dst_[s] * SCALER_FE;
            tA[s] = u0 + vc[s][0];
            tB[s] = u1 + vc[s][1];
            tC[s] = u2 + vc[s][2];
        } else {
            fe_[s] = 0.f; tA[s] = 0.f; tB[s] = 0.f; tC[s] = 0.f;
        }
    }

    float incl[4], tot[4];
    #pragma unroll
    for (int s = 0; s < 4; ++s) incl[s] = dpp_scan_incl(fe_[s]);
    #pragma unroll
    for (int s = 0; s < 4; ++s) tot[s] = __shfl(incl[s], 63, 64);

    float p_[4];
    float base = 0.f;
    #pragma unroll
    for (int s = 0; s < 4; ++s) {
        const float e = base + incl[s] - fe_[s];
        p_[s] = (1.0f - __expf(-fe_[s])) * __expf(-e);
        base += tot[s];
    }
    #pragma unroll
    for (int s = 0; s < 4; ++s) {
        out_probs[rayBase + lane + 64 * s] = p_[s];
    }

    float sp = dpp_scan_incl(p_[0] + p_[1] + p_[2] + p_[3]);
    float sd = dpp_scan_incl(dep_[0] * p_[0] + dep_[1] * p_[1] +
                             dep_[2] * p_[2] + dep_[3] * p_[3]);
    float c0 = dpp_scan_incl(tA[0] * p_[0] + tA[1] * p_[1] + tA[2] * p_[2] + tA[3] * p_[3]);
    float c1 = dpp_scan_incl(tB[0] * p_[0] + tB[1] * p_[1] + tB[2] * p_[2] + tB[3] * p_[3]);
    float c2 = dpp_scan_incl(tC[0] * p_[0] + tC[1] * p_[1] + tC[2] * p_[2] + tC[3] * p_[3]);
    if (lane == 63) {
        out_colors[ray * 3 + 0] = c0;
        out_colors[ray * 3 + 1] = c1;
        out_colors[ray * 3 + 2] = c2;
        out_depths[ray] = sd;
        out_missed[ray] = 1.0f - sp;
    }
}

extern "C" void kernel_launch(void* const* d_in, const int* in_sizes, int n_in,
                              void* d_out, int out_size, void* d_ws, size_t ws_size,
                              hipStream_t stream) {
    const float* ray_start  = (const float*)d_in[0];
    const float* ray_dir    = (const float*)d_in[1];
    const float* depth      = (const float*)d_in[2];
    const float* dists      = (const float*)d_in[3];
    const int*   vidx       = (const int*)d_in[4];
    const float* vcol       = (const float*)d_in[5];
    const float* W1         = (const float*)d_in[6];
    const float* b1         = (const float*)d_in[7];
    const float* w_sigma    = (const float*)d_in[8];
    const float* b_sigma    = (const float*)d_in[9];
    const float* W_tex      = (const float*)d_in[10];
    const float* b_tex      = (const float*)d_in[11];

    const int N = in_sizes[0] / 3;       // 4096 rays
    float* out        = (float*)d_out;
    float* out_colors = out;
    float* out_depths = out + (size_t)N * 3;
    float* out_missed = out + (size_t)N * 3 + N;
    float* out_probs  = out + (size_t)N * 3 + 2 * (size_t)N;

    volrend_kernel<<<N / 4, 256, 0, stream>>>(
        ray_start, ray_dir, depth, dists, vidx, vcol,
        W1, b1, w_sigma, b_sigma, W_tex, b_tex,
        out_colors, out_depths, out_missed, out_probs);
}